// Round 3
// baseline (300.217 us; speedup 1.0000x reference)
//
#include <hip/hip_runtime.h>
#include <cstdint>

#define NPIX (512 * 512)

typedef float f32x4 __attribute__((ext_vector_type(4)));
typedef float f32x2 __attribute__((ext_vector_type(2)));

#if __has_builtin(__builtin_amdgcn_sbfe)
#define SEL1(m, k) __builtin_amdgcn_sbfe((m), (k), 1)   // v_bfe_i32: 0 or -1 in one op
#else
#define SEL1(m, k) (-(((m) >> (k)) & 1))
#endif

// ---------------- Stage A: argmax over 16 ch + passthrough copy + mask pyramids ----------------
// 256 blocks, each owns an 8-row x 128-col tile (by = b>>2, bx = b&3).
// Thread t: row r = t>>5, cols c4 = (t&31)*4 -> 4 pixels via float4 (16 B/lane, full-width).
// Labels staged in LDS; after barrier t<128 do coalesced 64b label stores, t in [128,144)
// each compute one 8x8 mask cell (m1 4x4, m2 2x2, m3 1) exactly as the old standalone K2.
__global__ __launch_bounds__(256) void k_stageA(
    const float* __restrict__ enc, float* __restrict__ outc, uint8_t* __restrict__ labels,
    uint16_t* __restrict__ m1o, uint16_t* __restrict__ m2o, uint16_t* __restrict__ m3o,
    float* __restrict__ vecz, unsigned* __restrict__ cnt) {
  __shared__ uint8_t lab[8][128];
  int t = threadIdx.x, b = blockIdx.x;
  if (b == 0) {                                   // fresh zero every call (ws is 0xAA-poisoned)
    for (int i = t; i < 16 * 480; i += 256) vecz[i] = 0.f;
    if (t == 0) { cnt[0] = 0u; cnt[1] = 0u; }
  }
  int by = b >> 2, bx = b & 3;
  int r = t >> 5, c4 = (t & 31) * 4;
  size_t p = (size_t)(by * 8 + r) * 512 + bx * 128 + c4;
  f32x4 v = __builtin_nontemporal_load((const f32x4*)(enc + p));
  __builtin_nontemporal_store(v, (f32x4*)(outc + p));
  float b0 = v.x, b1v = v.y, b2v = v.z, b3v = v.w;
  int i0 = 0, i1 = 0, i2 = 0, i3 = 0;
  #pragma unroll
  for (int c = 1; c < 16; ++c) {
    v = __builtin_nontemporal_load((const f32x4*)(enc + (size_t)c * NPIX + p));
    __builtin_nontemporal_store(v, (f32x4*)(outc + (size_t)c * NPIX + p));
    if (v.x > b0) { b0 = v.x; i0 = c; }           // strict > keeps first index (argmax tie rule)
    if (v.y > b1v) { b1v = v.y; i1 = c; }
    if (v.z > b2v) { b2v = v.z; i2 = c; }
    if (v.w > b3v) { b3v = v.w; i3 = c; }
  }
  *(uint32_t*)&lab[r][c4] =
      (uint32_t)i0 | ((uint32_t)i1 << 8) | ((uint32_t)i2 << 16) | ((uint32_t)i3 << 24);
  __syncthreads();
  if (t < 128) {                                  // coalesced label store: 8 rows x 16 qwords
    int rr = t >> 4, q = t & 15;
    *(uint64_t*)(labels + (size_t)(by * 8 + rr) * 512 + bx * 128 + q * 8) =
        *(const uint64_t*)&lab[rr][q * 8];
  } else if (t < 144) {                           // one 8x8 mask cell per lane
    int cell = t - 128;
    uint64_t rows[8];
    #pragma unroll
    for (int rr = 0; rr < 8; ++rr) rows[rr] = *(const uint64_t*)&lab[rr][cell * 8];
    uint16_t m1v[4][4];
    uint16_t m2v[2][2] = {{0, 0}, {0, 0}};
    #pragma unroll
    for (int i = 0; i < 4; ++i) {
      uint64_t ra = rows[2 * i], rb = rows[2 * i + 1];
      #pragma unroll
      for (int j = 0; j < 4; ++j) {
        unsigned sh = 16u * j;
        uint16_t m = (uint16_t)((1u << ((ra >> sh) & 0xFF)) | (1u << ((ra >> (sh + 8)) & 0xFF)) |
                                (1u << ((rb >> sh) & 0xFF)) | (1u << ((rb >> (sh + 8)) & 0xFF)));
        m1v[i][j] = m;
        m2v[i >> 1][j >> 1] |= m;
      }
    }
    int x3 = bx * 16 + cell, y3 = by;
    #pragma unroll
    for (int i = 0; i < 4; ++i) {
      uint64_t pack = (uint64_t)m1v[i][0] | ((uint64_t)m1v[i][1] << 16) |
                      ((uint64_t)m1v[i][2] << 32) | ((uint64_t)m1v[i][3] << 48);
      *(uint64_t*)(m1o + (size_t)(y3 * 4 + i) * 256 + x3 * 4) = pack;
    }
    #pragma unroll
    for (int i = 0; i < 2; ++i) {
      uint32_t pack = (uint32_t)m2v[i][0] | ((uint32_t)m2v[i][1] << 16);
      *(uint32_t*)(m2o + (size_t)(y3 * 2 + i) * 128 + x3 * 2) = pack;
    }
    m3o[y3 * 64 + x3] = (uint16_t)(m2v[0][0] | m2v[0][1] | m2v[1][0] | m2v[1][1]);
  }
}

// ---------------- Stage B: level0 (0..1023) + bitmask levels (1024..1791) + fused MLP tail ----------------
// All B-work only atomicMax's into vec_u (order-free). Every block bumps cnt[0] when done;
// blocks 0..15 spin (agent-acquire + s_sleep) until cnt[0]==1792, then each computes one row of
// hid = vec@W1+b1 (240 cols, W1 coalesced, vec row broadcast from LDS); last-done block (cnt[1])
// runs mlp2. LDS is a 19.3 KB union so B-phase occupancy (~8 blocks/CU) is unchanged.
// Deadlock-safe: 16 spinners (dispatched first) vs >=1500 resident slots for 1776 workers.
__global__ __launch_bounds__(256) void k_stageB(
    const float* __restrict__ f0, const uint8_t* __restrict__ labels,
    const float* __restrict__ f1, const float* __restrict__ f2, const float* __restrict__ f3,
    const uint16_t* __restrict__ m1, const uint16_t* __restrict__ m2, const uint16_t* __restrict__ m3,
    unsigned* __restrict__ vec_u, const float* __restrict__ vecf,
    const float* __restrict__ W1, const float* __restrict__ b1,
    const float* __restrict__ W2, const float* __restrict__ b2,
    float* __restrict__ hid, float* __restrict__ out, unsigned* __restrict__ cnt) {
  __shared__ union {
    unsigned sAcc[4][16][65];                     // B-phase accumulators (16.6 KB)
    float vrow[480];                              // mlp1: one vec row (1.9 KB)
    struct { float h2[16 * 241]; float w2s[960]; } s2;  // mlp2 (19.3 KB) -> union max
  } u;
  __shared__ unsigned lastv;
  int t = threadIdx.x;
  int b = blockIdx.x;
  if (b < 1024) {
    // ---- level 0: f0 (32ch x 512^2), LDS atomic max, 8 channels/block ----
    unsigned* s = &u.sAcc[0][0][0];               // stride 33: bank = (label+c)%32
    for (int i = t; i < 16 * 33; i += 256) s[i] = 0u;
    __syncthreads();
    int cg = b & 3;                               // channel group (8 channels)
    int g = (b >> 2) * 256 + t;                   // float4 pixel group, 65536 total
    uchar4 lb = *(const uchar4*)(labels + g * 4);
    const f32x4* f4 = (const f32x4*)f0;
    const int s4 = NPIX / 4;
    #pragma unroll
    for (int cc = 0; cc < 8; ++cc) {
      int c = cg * 8 + cc;
      f32x4 v = __builtin_nontemporal_load(f4 + c * s4 + g);   // single-use stream
      atomicMax(&s[lb.x * 33 + c], __float_as_uint(fmaxf(v.x, 0.f)));
      atomicMax(&s[lb.y * 33 + c], __float_as_uint(fmaxf(v.y, 0.f)));
      atomicMax(&s[lb.z * 33 + c], __float_as_uint(fmaxf(v.z, 0.f)));
      atomicMax(&s[lb.w * 33 + c], __float_as_uint(fmaxf(v.w, 0.f)));
    }
    __syncthreads();
    if (t < 128) {
      int k = t >> 3, c = cg * 8 + (t & 7);
      atomicMax(&vec_u[k * 480 + c], s[k * 33 + c]);
    }
  } else {
    // ---- bitmask levels f1/f2/f3 (R4 grid + 2-deep prefetch) ----
    int bb = b - 1024;
    const float* f; const uint16_t* masks; int P, lnChunks, vecBase;
    if (bb < 256)      { f = f1; masks = m1; P = 65536; lnChunks = 4; vecBase = 32; }
    else if (bb < 512) { bb -= 256; f = f2; masks = m2; P = 16384; lnChunks = 3; vecBase = 96; }
    else               { bb -= 512; f = f3; masks = m3; P = 4096;  lnChunks = 2; vecBase = 224; }
    int wave = t >> 6, lane = t & 63;
    int nChunks = 1 << lnChunks;
    int chunk = bb & (nChunks - 1);
    int cg = bb >> lnChunks;
    int c = cg * 4 + wave;
    int chunkSize = P >> lnChunks;                // 4096 / 2048 / 1024
    int base = chunk * chunkSize;
    const f32x4* fp4 = (const f32x4*)(f + (size_t)c * P + base) + lane;
    const uint64_t* mp8 = (const uint64_t*)(masks + base) + lane;
    int acc[16];
    #pragma unroll
    for (int k = 0; k < 16; ++k) acc[k] = 0;
    int nIter = chunkSize >> 8;                   // 16 / 8 / 4 (4 px/lane/iter)
    f32x4 v = __builtin_nontemporal_load(fp4);
    uint64_t mm = *mp8;
    for (int it = 0; it < nIter; ++it) {
      f32x4 vn = v; uint64_t mn = mm;
      if (it + 1 < nIter) {                       // wave-uniform branch; prefetch next iter
        vn = __builtin_nontemporal_load(fp4 + (it + 1) * 64);
        mn = mp8[(it + 1) * 32];
      }
      int vb0 = __float_as_int(fmaxf(v.x, 0.f)), vb1 = __float_as_int(fmaxf(v.y, 0.f));
      int vb2 = __float_as_int(fmaxf(v.z, 0.f)), vb3 = __float_as_int(fmaxf(v.w, 0.f));
      int m0 = (int)(mm & 0xFFFF), m1x = (int)((mm >> 16) & 0xFFFF);
      int m2x = (int)((mm >> 32) & 0xFFFF), m3x = (int)(mm >> 48);
      #pragma unroll
      for (int k = 0; k < 16; ++k) {
        int a01 = max(vb0 & SEL1(m0, k), vb1 & SEL1(m1x, k));
        int a23 = max(vb2 & SEL1(m2x, k), vb3 & SEL1(m3x, k));
        acc[k] = max(acc[k], max(a01, a23));      // vb >= 0 => int max == float max
      }
      v = vn; mm = mn;
    }
    #pragma unroll
    for (int k = 0; k < 16; ++k) u.sAcc[wave][k][lane] = (unsigned)acc[k];
    __syncthreads();
    int w = t >> 6, l = t & 63;
    int k = l >> 2, part = l & 3;
    const unsigned* row = &u.sAcc[w][k][part * 16];
    unsigned r = row[0];
    #pragma unroll
    for (int j = 1; j < 16; ++j) r = max(r, row[j]);
    r = max(r, (unsigned)__shfl_xor((int)r, 1, 64));
    r = max(r, (unsigned)__shfl_xor((int)r, 2, 64));
    if (part == 0)
      atomicMax(&vec_u[k * 480 + vecBase + cg * 4 + w], r);
  }
  // ---- completion protocol ----
  __threadfence();                                // release vec_u atomics before counting
  __syncthreads();                                // also: LDS reads done before union reuse
  if (t == 0) atomicAdd(&cnt[0], 1u);
  if (blockIdx.x >= 16) return;
  // ---- mlp1 (blocks 0..15): row r of hid = vec[r,:] @ W1 + b1 ----
  if (t == 0) {
    while (__hip_atomic_load(&cnt[0], __ATOMIC_ACQUIRE, __HIP_MEMORY_SCOPE_AGENT) < 1792u)
      __builtin_amdgcn_s_sleep(8);
  }
  __syncthreads();
  int mr = blockIdx.x;
  for (int i = t; i < 480; i += 256) u.vrow[i] = vecf[mr * 480 + i];
  __syncthreads();
  if (t < 240) {
    float a0 = 0.f, a1 = 0.f, a2 = 0.f, a3 = 0.f;
    for (int j = 0; j < 480; j += 4) {            // W1 cols coalesced across lanes; vrow broadcast
      a0 += u.vrow[j]     * W1[j * 240 + t];
      a1 += u.vrow[j + 1] * W1[(j + 1) * 240 + t];
      a2 += u.vrow[j + 2] * W1[(j + 2) * 240 + t];
      a3 += u.vrow[j + 3] * W1[(j + 3) * 240 + t];
    }
    hid[mr * 240 + t] = a0 + a1 + a2 + a3 + b1[t];
  }
  // canonical threadFenceReduction: release hid, count, winner consumes
  __threadfence();
  __syncthreads();                                // all reads of vrow done before union reuse
  if (t == 0) lastv = atomicAdd(&cnt[1], 1u);
  __syncthreads();
  if (lastv != 15) return;
  __threadfence();                                // acquire side
  // ---- mlp2 (winner block): bbox = sigmoid(hid(16x240) @ W2(240x4) + b2), rows 1..15 ----
  for (int i = t; i < 16 * 240; i += 256) {
    int rr = i / 240, j = i - rr * 240;
    u.s2.h2[rr * 241 + j] = hid[i];
  }
  for (int i = t; i < 960; i += 256) u.s2.w2s[i] = W2[i];
  __syncthreads();
  if (t < 64) {
    int k = t >> 2, o = t & 3;
    const float* hk = u.s2.h2 + k * 241;
    float a0 = b2[o], a1 = 0.f;
    for (int j = 0; j < 240; j += 2) {
      a0 += hk[j]     * u.s2.w2s[j * 4 + o];
      a1 += hk[j + 1] * u.s2.w2s[(j + 1) * 4 + o];
    }
    float a = a0 + a1;
    float s = 1.f / (1.f + __expf(-a));
    if (k >= 1) out[(k - 1) * 4 + o] = s;         // rows 1..15 only
  }
}

extern "C" void kernel_launch(void* const* d_in, const int* in_sizes, int n_in,
                              void* d_out, int out_size, void* d_ws, size_t ws_size,
                              hipStream_t stream) {
  const float* enc = (const float*)d_in[0];
  const float* f0  = (const float*)d_in[1];
  const float* f1  = (const float*)d_in[2];
  const float* f2  = (const float*)d_in[3];
  const float* f3  = (const float*)d_in[4];
  const float* W1  = (const float*)d_in[5];
  const float* b1  = (const float*)d_in[6];
  const float* W2  = (const float*)d_in[7];
  const float* b2  = (const float*)d_in[8];
  float* out = (float*)d_out;                 // [0:60) bboxes, [60:) encoded copy
  char* ws = (char*)d_ws;

  uint8_t*  labels = (uint8_t*)ws;                     // 262144 B
  uint16_t* m1     = (uint16_t*)(ws + 262144);         // 131072 B
  uint16_t* m2     = (uint16_t*)(ws + 393216);         //  32768 B
  uint16_t* m3     = (uint16_t*)(ws + 425984);         //   8192 B
  float*    vec    = (float*)(ws + 434176);            //  30720 B (16 x 480)
  float*    hid    = (float*)(ws + 464896);            //  15360 B (16 x 240)
  unsigned* cnt    = (unsigned*)(ws + 480256);         //      8 B (B-done, mlp1-done counters)
  unsigned* vec_u  = (unsigned*)vec;

  k_stageA<<<256, 256, 0, stream>>>(enc, out + 60, labels, m1, m2, m3, vec, cnt);
  k_stageB<<<1792, 256, 0, stream>>>(f0, labels, f1, f2, f3, m1, m2, m3,
                                     vec_u, vec, W1, b1, W2, b2, hid, out, cnt);
}

// Round 4
// 154.204 us; speedup vs baseline: 1.9469x; 1.9469x over previous
//
#include <hip/hip_runtime.h>
#include <cstdint>

#define NPIX (512 * 512)

typedef float f32x4 __attribute__((ext_vector_type(4)));

#if __has_builtin(__builtin_amdgcn_sbfe)
#define SEL1(m, k) __builtin_amdgcn_sbfe((m), (k), 1)   // v_bfe_i32: 0 or -1 in one op
#else
#define SEL1(m, k) (-(((m) >> (k)) & 1))
#endif

// ---------------- Stage A: argmax over 16 ch + passthrough copy + mask pyramids ----------------
// 256 blocks, each owns an 8-row x 128-col tile (by = b>>2, bx = b&3).
// Thread t: row r = t>>5, cols c4 = (t&31)*4 -> 4 pixels via float4 (16 B/lane, full-width).
// Labels staged in LDS; after barrier t<128 do coalesced 64b label stores, t in [128,144)
// each compute one 8x8 mask cell (m1 4x4, m2 2x2, m3 1) exactly as the old standalone K2.
// NOTE (R3 post-mortem): cross-block spin-wait fusion of the MLP into stage B regressed 155->300us.
// Agent-scope acquire polls invalidate the local XCD L2 every iteration (~us each, serialized) --
// the spin tail alone was ~175us. Keep separate dispatches; 1.4us/launch is the cheaper price.
__global__ __launch_bounds__(256) void k_stageA(
    const float* __restrict__ enc, float* __restrict__ outc, uint8_t* __restrict__ labels,
    uint16_t* __restrict__ m1o, uint16_t* __restrict__ m2o, uint16_t* __restrict__ m3o,
    float* __restrict__ vecz, unsigned* __restrict__ cnt) {
  __shared__ uint8_t lab[8][128];
  int t = threadIdx.x, b = blockIdx.x;
  if (b == 0) {                                   // fresh zero every call (ws is 0xAA-poisoned)
    for (int i = t; i < 16 * 480; i += 256) vecz[i] = 0.f;
    if (t == 0) cnt[0] = 0u;
  }
  int by = b >> 2, bx = b & 3;
  int r = t >> 5, c4 = (t & 31) * 4;
  size_t p = (size_t)(by * 8 + r) * 512 + bx * 128 + c4;
  f32x4 v = __builtin_nontemporal_load((const f32x4*)(enc + p));
  __builtin_nontemporal_store(v, (f32x4*)(outc + p));
  float b0 = v.x, b1v = v.y, b2v = v.z, b3v = v.w;
  int i0 = 0, i1 = 0, i2 = 0, i3 = 0;
  #pragma unroll
  for (int c = 1; c < 16; ++c) {
    v = __builtin_nontemporal_load((const f32x4*)(enc + (size_t)c * NPIX + p));
    __builtin_nontemporal_store(v, (f32x4*)(outc + (size_t)c * NPIX + p));
    if (v.x > b0) { b0 = v.x; i0 = c; }           // strict > keeps first index (argmax tie rule)
    if (v.y > b1v) { b1v = v.y; i1 = c; }
    if (v.z > b2v) { b2v = v.z; i2 = c; }
    if (v.w > b3v) { b3v = v.w; i3 = c; }
  }
  *(uint32_t*)&lab[r][c4] =
      (uint32_t)i0 | ((uint32_t)i1 << 8) | ((uint32_t)i2 << 16) | ((uint32_t)i3 << 24);
  __syncthreads();
  if (t < 128) {                                  // coalesced label store: 8 rows x 16 qwords
    int rr = t >> 4, q = t & 15;
    *(uint64_t*)(labels + (size_t)(by * 8 + rr) * 512 + bx * 128 + q * 8) =
        *(const uint64_t*)&lab[rr][q * 8];
  } else if (t < 144) {                           // one 8x8 mask cell per lane
    int cell = t - 128;
    uint64_t rows[8];
    #pragma unroll
    for (int rr = 0; rr < 8; ++rr) rows[rr] = *(const uint64_t*)&lab[rr][cell * 8];
    uint16_t m1v[4][4];
    uint16_t m2v[2][2] = {{0, 0}, {0, 0}};
    #pragma unroll
    for (int i = 0; i < 4; ++i) {
      uint64_t ra = rows[2 * i], rb = rows[2 * i + 1];
      #pragma unroll
      for (int j = 0; j < 4; ++j) {
        unsigned sh = 16u * j;
        uint16_t m = (uint16_t)((1u << ((ra >> sh) & 0xFF)) | (1u << ((ra >> (sh + 8)) & 0xFF)) |
                                (1u << ((rb >> sh) & 0xFF)) | (1u << ((rb >> (sh + 8)) & 0xFF)));
        m1v[i][j] = m;
        m2v[i >> 1][j >> 1] |= m;
      }
    }
    int x3 = bx * 16 + cell, y3 = by;
    #pragma unroll
    for (int i = 0; i < 4; ++i) {
      uint64_t pack = (uint64_t)m1v[i][0] | ((uint64_t)m1v[i][1] << 16) |
                      ((uint64_t)m1v[i][2] << 32) | ((uint64_t)m1v[i][3] << 48);
      *(uint64_t*)(m1o + (size_t)(y3 * 4 + i) * 256 + x3 * 4) = pack;
    }
    #pragma unroll
    for (int i = 0; i < 2; ++i) {
      uint32_t pack = (uint32_t)m2v[i][0] | ((uint32_t)m2v[i][1] << 16);
      *(uint32_t*)(m2o + (size_t)(y3 * 2 + i) * 128 + x3 * 2) = pack;
    }
    m3o[y3 * 64 + x3] = (uint16_t)(m2v[0][0] | m2v[0][1] | m2v[1][0] | m2v[1][1]);
  }
}

// ---------------- Stage B: level0 (blocks 0..1023) + bitmask levels f1/f2/f3 (1024..1791) ----------------
// Both halves only atomicMax into vec_u (order-free), so they overlap freely; entire 1792-block
// grid is co-resident at ~7 blocks/CU.
__global__ __launch_bounds__(256) void k_stageB(
    const float* __restrict__ f0, const uint8_t* __restrict__ labels,
    const float* __restrict__ f1, const float* __restrict__ f2, const float* __restrict__ f3,
    const uint16_t* __restrict__ m1, const uint16_t* __restrict__ m2, const uint16_t* __restrict__ m3,
    unsigned* __restrict__ vec_u) {
  __shared__ unsigned sAcc[4][16][65];            // K4 layout; K3 aliases first 528 words
  int b = blockIdx.x;
  if (b < 1024) {
    // ---- level 0: f0 (32ch x 512^2), LDS atomic max, 8 channels/block ----
    unsigned* s = &sAcc[0][0][0];                 // stride 33: bank = (label+c)%32
    for (int i = threadIdx.x; i < 16 * 33; i += 256) s[i] = 0u;
    __syncthreads();
    int cg = b & 3;                               // channel group (8 channels)
    int g = (b >> 2) * 256 + threadIdx.x;         // float4 pixel group, 65536 total
    uchar4 lb = *(const uchar4*)(labels + g * 4);
    const f32x4* f4 = (const f32x4*)f0;
    const int s4 = NPIX / 4;
    #pragma unroll
    for (int cc = 0; cc < 8; ++cc) {
      int c = cg * 8 + cc;
      f32x4 v = __builtin_nontemporal_load(f4 + c * s4 + g);   // single-use stream
      atomicMax(&s[lb.x * 33 + c], __float_as_uint(fmaxf(v.x, 0.f)));
      atomicMax(&s[lb.y * 33 + c], __float_as_uint(fmaxf(v.y, 0.f)));
      atomicMax(&s[lb.z * 33 + c], __float_as_uint(fmaxf(v.z, 0.f)));
      atomicMax(&s[lb.w * 33 + c], __float_as_uint(fmaxf(v.w, 0.f)));
    }
    __syncthreads();
    if (threadIdx.x < 128) {
      int k = threadIdx.x >> 3, c = cg * 8 + (threadIdx.x & 7);
      atomicMax(&vec_u[k * 480 + c], s[k * 33 + c]);
    }
  } else {
    // ---- bitmask levels (R4 grid + 2-deep prefetch) ----
    b -= 1024;
    const float* f; const uint16_t* masks; int P, lnChunks, vecBase;
    if (b < 256)      { f = f1; masks = m1; P = 65536; lnChunks = 4; vecBase = 32; }
    else if (b < 512) { b -= 256; f = f2; masks = m2; P = 16384; lnChunks = 3; vecBase = 96; }
    else              { b -= 512; f = f3; masks = m3; P = 4096;  lnChunks = 2; vecBase = 224; }
    int wave = threadIdx.x >> 6, lane = threadIdx.x & 63;
    int nChunks = 1 << lnChunks;
    int chunk = b & (nChunks - 1);
    int cg = b >> lnChunks;
    int c = cg * 4 + wave;
    int chunkSize = P >> lnChunks;                // 4096 / 2048 / 1024
    int base = chunk * chunkSize;
    const f32x4* fp4 = (const f32x4*)(f + (size_t)c * P + base) + lane;
    const uint64_t* mp8 = (const uint64_t*)(masks + base) + lane;
    int acc[16];
    #pragma unroll
    for (int k = 0; k < 16; ++k) acc[k] = 0;
    int nIter = chunkSize >> 8;                   // 16 / 8 / 4 (4 px/lane/iter)
    f32x4 v = __builtin_nontemporal_load(fp4);
    uint64_t mm = *mp8;
    for (int it = 0; it < nIter; ++it) {
      f32x4 vn = v; uint64_t mn = mm;
      if (it + 1 < nIter) {                       // wave-uniform branch; prefetch next iter
        vn = __builtin_nontemporal_load(fp4 + (it + 1) * 64);
        mn = mp8[(it + 1) * 32];
      }
      int vb0 = __float_as_int(fmaxf(v.x, 0.f)), vb1 = __float_as_int(fmaxf(v.y, 0.f));
      int vb2 = __float_as_int(fmaxf(v.z, 0.f)), vb3 = __float_as_int(fmaxf(v.w, 0.f));
      int m0 = (int)(mm & 0xFFFF), m1x = (int)((mm >> 16) & 0xFFFF);
      int m2x = (int)((mm >> 32) & 0xFFFF), m3x = (int)(mm >> 48);
      #pragma unroll
      for (int k = 0; k < 16; ++k) {
        int a01 = max(vb0 & SEL1(m0, k), vb1 & SEL1(m1x, k));
        int a23 = max(vb2 & SEL1(m2x, k), vb3 & SEL1(m3x, k));
        acc[k] = max(acc[k], max(a01, a23));      // vb >= 0 => int max == float max
      }
      v = vn; mm = mn;
    }
    #pragma unroll
    for (int k = 0; k < 16; ++k) sAcc[wave][k][lane] = (unsigned)acc[k];
    __syncthreads();
    int w = threadIdx.x >> 6, l = threadIdx.x & 63;
    int k = l >> 2, part = l & 3;
    const unsigned* row = &sAcc[w][k][part * 16];
    unsigned r = row[0];
    #pragma unroll
    for (int j = 1; j < 16; ++j) r = max(r, row[j]);
    r = max(r, (unsigned)__shfl_xor((int)r, 1, 64));
    r = max(r, (unsigned)__shfl_xor((int)r, 2, 64));
    if (part == 0)
      atomicMax(&vec_u[k * 480 + vecBase + cg * 4 + w], r);
  }
}

// ---------------- Stage C: mlp1 (30 blocks) + last-block-done mlp2 ----------------
// LDS: mlp1 buffers (v,w) and mlp2 buffers (h2,w2s) share storage via union — mlp2 runs
// strictly after the winner block's last read of v/w (barrier after atomicAdd). Total 46.3 KB.
__global__ __launch_bounds__(256) void k_mlp(
    const float* __restrict__ vecf, const float* __restrict__ W1, const float* __restrict__ b1,
    const float* __restrict__ W2, const float* __restrict__ b2,
    float* __restrict__ hid, float* __restrict__ out, unsigned* __restrict__ cnt) {
  __shared__ union {
    struct { float v[16 * 484]; float w[480 * 8]; } s1;   // 30976 + 15360 B
    struct { float h2[16 * 241]; float w2s[960]; } s2;    // 15424 + 3840 B
  } u;
  __shared__ unsigned lastv;
  int t = threadIdx.x;
  int colBase = blockIdx.x * 8;
  float* v = u.s1.v;
  float* w = u.s1.w;
  for (int i = t; i < 16 * 480; i += 256) {
    int r = i / 480, j = i - r * 480;
    v[r * 484 + j] = vecf[i];
  }
  for (int i = t; i < 480 * 8; i += 256) {
    int j = i >> 3, col = i & 7;
    w[i] = W1[j * 240 + colBase + col];
  }
  __syncthreads();
  if (t < 128) {
    int r = t >> 3, col = t & 7;
    const float* vr = v + r * 484;
    float a0 = 0.f, a1 = 0.f, a2 = 0.f, a3 = 0.f;
    for (int j = 0; j < 480; j += 4) {
      a0 += vr[j]     * w[j * 8 + col];
      a1 += vr[j + 1] * w[(j + 1) * 8 + col];
      a2 += vr[j + 2] * w[(j + 2) * 8 + col];
      a3 += vr[j + 3] * w[(j + 3) * 8 + col];
    }
    hid[r * 240 + colBase + col] = a0 + a1 + a2 + a3 + b1[colBase + col];
  }
  // canonical threadFenceReduction pattern: release writes, count blocks, winner consumes
  __threadfence();
  __syncthreads();                                // all reads of v/w done before LDS reuse
  if (t == 0) lastv = atomicAdd(cnt, 1u);
  __syncthreads();
  if (lastv != 29) return;
  __threadfence();                                // acquire side
  // ---- mlp2: bbox = sigmoid(hid(16x240) @ W2(240x4) + b2), rows 1..15 ----
  float* h2 = u.s2.h2;
  float* w2s = u.s2.w2s;
  for (int i = t; i < 16 * 240; i += 256) {
    int r = i / 240, j = i - r * 240;
    h2[r * 241 + j] = hid[i];
  }
  for (int i = t; i < 960; i += 256) w2s[i] = W2[i];
  __syncthreads();
  if (t < 64) {
    int k = t >> 2, o = t & 3;
    const float* hk = h2 + k * 241;
    float a0 = b2[o], a1 = 0.f;
    for (int j = 0; j < 240; j += 2) {
      a0 += hk[j]     * w2s[j * 4 + o];
      a1 += hk[j + 1] * w2s[(j + 1) * 4 + o];
    }
    float a = a0 + a1;
    float s = 1.f / (1.f + __expf(-a));
    if (k >= 1) out[(k - 1) * 4 + o] = s;         // rows 1..15 only
  }
}

extern "C" void kernel_launch(void* const* d_in, const int* in_sizes, int n_in,
                              void* d_out, int out_size, void* d_ws, size_t ws_size,
                              hipStream_t stream) {
  const float* enc = (const float*)d_in[0];
  const float* f0  = (const float*)d_in[1];
  const float* f1  = (const float*)d_in[2];
  const float* f2  = (const float*)d_in[3];
  const float* f3  = (const float*)d_in[4];
  const float* W1  = (const float*)d_in[5];
  const float* b1  = (const float*)d_in[6];
  const float* W2  = (const float*)d_in[7];
  const float* b2  = (const float*)d_in[8];
  float* out = (float*)d_out;                 // [0:60) bboxes, [60:) encoded copy
  char* ws = (char*)d_ws;

  uint8_t*  labels = (uint8_t*)ws;                     // 262144 B
  uint16_t* m1     = (uint16_t*)(ws + 262144);         // 131072 B
  uint16_t* m2     = (uint16_t*)(ws + 393216);         //  32768 B
  uint16_t* m3     = (uint16_t*)(ws + 425984);         //   8192 B
  float*    vec    = (float*)(ws + 434176);            //  30720 B (16 x 480)
  float*    hid    = (float*)(ws + 464896);            //  15360 B (16 x 240)
  unsigned* cnt    = (unsigned*)(ws + 480256);         //      4 B (stage-C block counter)
  unsigned* vec_u  = (unsigned*)vec;

  k_stageA<<<256, 256, 0, stream>>>(enc, out + 60, labels, m1, m2, m3, vec, cnt);
  k_stageB<<<1792, 256, 0, stream>>>(f0, labels, f1, f2, f3, m1, m2, m3, vec_u);
  k_mlp<<<30, 256, 0, stream>>>(vec, W1, b1, W2, b2, hid, out, cnt);
}